// Round 9
// baseline (73.963 us; speedup 1.0000x reference)
//
#include <hip/hip_runtime.h>
#include <hip/hip_bf16.h>

typedef _Float16 half8 __attribute__((ext_vector_type(8)));
typedef float    floatx4 __attribute__((ext_vector_type(4)));

#define WSCALE      4096.0f
#define WSCALE_INV  (1.0f/(4096.0f*4096.0f))

// ws layout (float offsets)
#define T1_OFF   0      // 4096 floats (16,16,16)
#define U_OFF    4096   // 4096 floats (16,4,4,4,4)
#define WF16_OFF 8192   // 65536 _Float16, fragment-major; 16B-aligned

// ---- Prep 1: TWO INDEPENDENT blocks, register-tiled (4x4, ds_read_b128) ----
// block 0: cores 0-3 -> S0,S1 (LDS) -> T1 -> ws
// block 1: cores 4-7 -> S2,S3 (LDS) -> U  -> ws
// All layouts byte-identical to the verified R8 scalar version.
__global__ __launch_bounds__(256)
void mpo_prep1(const float* __restrict__ w, float* __restrict__ ws) {
    __shared__ __align__(16) float wL[3136];
    __shared__ __align__(16) float sL[4352];
    const int tid = threadIdx.x;

    // stage this block's 4 cores (3136 floats) as float4
    {
        const floatx4* s4 = reinterpret_cast<const floatx4*>(w + blockIdx.x * 3136);
        floatx4* d4 = reinterpret_cast<floatx4*>(wL);
        for (int i = tid; i < 784; i += 256) d4[i] = s4[i];
    }
    __syncthreads();

    if (blockIdx.x == 0) {
        // ---- S0 (256 outs, scalar): sL[c*16+kk*4+mm] ----
        {
            int li = tid;
            int mm = li & 3, kk = (li >> 2) & 3, c = li >> 4;
            int k1 = kk >> 1, k2 = kk & 1, m1 = mm >> 1, m2 = mm & 1;
            float s = 0.f;
#pragma unroll
            for (int b = 0; b < 16; ++b)
                s += wL[b * 4 + k1 * 2 + m1] * wL[64 + b * 64 + c * 4 + k2 * 2 + m2];
            sL[li] = s;
        }
        // ---- S1 tiled: rows i=(a,k1,m1) 64, cols j=(c,k2,m2) 64, K=b ----
        {
            const int i0 = (tid >> 4) * 4, j0 = (tid & 15) * 4;
            const float* Ab = wL + 1088 + (i0 >> 2) * 64;   // + b*4 + r
            const float* Bb = wL + 2112 + j0;               // + b*64 + s
            float acc[4][4] = {};
#pragma unroll
            for (int b = 0; b < 16; ++b) {
                floatx4 ar = *reinterpret_cast<const floatx4*>(Ab + b * 4);
                floatx4 br = *reinterpret_cast<const floatx4*>(Bb + b * 64);
#pragma unroll
                for (int r = 0; r < 4; ++r)
#pragma unroll
                    for (int s = 0; s < 4; ++s) acc[r][s] += ar[r] * br[s];
            }
#pragma unroll
            for (int r = 0; r < 4; ++r)
#pragma unroll
            for (int s = 0; s < 4; ++s) {
                int i = i0 + r, j = j0 + s;
                sL[256 + (i >> 2) * 256 + (j >> 2) * 16 +
                   ((i >> 1) & 1) * 8 + ((j >> 1) & 1) * 4 + (i & 1) * 2 + (j & 1)] = acc[r][s];
            }
        }
        __syncthreads();
        // ---- T1 tiled: rows p=(I,J) 16, cols q=(b,k,m) 256, K=a ----
        {
            const int p0 = (tid >> 6) * 4, q0 = (tid & 63) * 4;
            float acc[4][4] = {};
#pragma unroll
            for (int a = 0; a < 16; ++a) {
                floatx4 pr = *reinterpret_cast<const floatx4*>(sL + a * 16 + p0);
                floatx4 qr = *reinterpret_cast<const floatx4*>(sL + 256 + a * 256 + q0);
#pragma unroll
                for (int r = 0; r < 4; ++r)
#pragma unroll
                    for (int s = 0; s < 4; ++s) acc[r][s] += pr[r] * qr[s];
            }
#pragma unroll
            for (int r = 0; r < 4; ++r)
#pragma unroll
            for (int s = 0; s < 4; ++s) {
                int p = p0 + r, q = q0 + s;
                ws[T1_OFF + (q >> 4) * 256 + ((p >> 2) * 4 + ((q >> 2) & 3)) * 16 +
                   (p & 3) * 4 + (q & 3)] = acc[r][s];
            }
        }
    } else {
        // ---- S2 tiled (cores 4,5): rows i=(a,k1,m1), cols j=(c,k2,m2), K=b ----
        {
            const int i0 = (tid >> 4) * 4, j0 = (tid & 15) * 4;
            const float* Ab = wL + (i0 >> 2) * 64;          // + b*4 + r
            const float* Bb = wL + 1024 + j0;               // + b*64 + s
            float acc[4][4] = {};
#pragma unroll
            for (int b = 0; b < 16; ++b) {
                floatx4 ar = *reinterpret_cast<const floatx4*>(Ab + b * 4);
                floatx4 br = *reinterpret_cast<const floatx4*>(Bb + b * 64);
#pragma unroll
                for (int r = 0; r < 4; ++r)
#pragma unroll
                    for (int s = 0; s < 4; ++s) acc[r][s] += ar[r] * br[s];
            }
#pragma unroll
            for (int r = 0; r < 4; ++r)
#pragma unroll
            for (int s = 0; s < 4; ++s) {
                int i = i0 + r, j = j0 + s;
                sL[(i >> 2) * 256 + (j >> 2) * 16 +
                   ((i >> 1) & 1) * 8 + ((j >> 1) & 1) * 4 + (i & 1) * 2 + (j & 1)] = acc[r][s];
            }
        }
        // ---- S3 (256 outs, scalar): sL[4096 + a*16 + kk*4 + mm] ----
        {
            int li = tid;
            int mm = li & 3, kk = (li >> 2) & 3, a = li >> 4;
            int k1 = kk >> 1, k2 = kk & 1, m1 = mm >> 1, m2 = mm & 1;
            float s = 0.f;
#pragma unroll
            for (int b = 0; b < 16; ++b)
                s += wL[2048 + a * 64 + b * 4 + k1 * 2 + m1] * wL[3072 + b * 4 + k2 * 2 + m2];
            sL[4096 + li] = s;
        }
        __syncthreads();
        // ---- U tiled: rows rho=(a,kc,mc) 256, cols q=(k2,m2) 16, K=b ----
        {
            const int r0 = (tid >> 2) * 4, q0 = (tid & 3) * 4;
            float acc[4][4] = {};
#pragma unroll
            for (int b = 0; b < 16; ++b) {
                floatx4 ar = *reinterpret_cast<const floatx4*>(sL + (r0 >> 4) * 256 + b * 16 + (r0 & 15));
                floatx4 br = *reinterpret_cast<const floatx4*>(sL + 4096 + b * 16 + q0);
#pragma unroll
                for (int r = 0; r < 4; ++r)
#pragma unroll
                    for (int s = 0; s < 4; ++s) acc[r][s] += ar[r] * br[s];
            }
#pragma unroll
            for (int r = 0; r < 4; ++r)
#pragma unroll
            for (int s = 0; s < 4; ++s)
                ws[U_OFF + (r0 + r) * 16 + q0 + s] = acc[r][s];
        }
    }
}

// ---- Prep 2 (unchanged, verified): W from T1 x U, fp16, fragment-major ----
__global__ __launch_bounds__(256)
void mpo_prep2(const float* __restrict__ ws, _Float16* __restrict__ Wf) {
    int idx = blockIdx.x * blockDim.x + threadIdx.x;   // 65536
    int J4 = idx & 255, I4 = idx >> 8;                 // col, k
    int I16 = I4 >> 4, kc = (I4 >> 2) & 3, k2 = I4 & 3;
    int J16 = J4 >> 4, mc = (J4 >> 2) & 3, m2 = J4 & 3;
    const float* T1 = ws + T1_OFF;
    const float* U  = ws + U_OFF + (((kc * 4 + mc) * 4 + k2) * 4 + m2);
    float s = 0.f;
#pragma unroll
    for (int a = 0; a < 16; ++a)
        s += T1[(a * 16 + I16) * 16 + J16] * U[a * 256];
    int n = J4 >> 4, lr = J4 & 15, kk = I4 >> 5, gg = (I4 >> 3) & 3, j = I4 & 7;
    Wf[(((n * 8 + kk) * 64) + gg * 16 + lr) * 8 + j] = (_Float16)(s * WSCALE);
}

// ---- Main fused kernel: validated R6-R8 structure + 2-DEEP x prefetch ----
// 256 blocks x 512 threads, W (128 KB) + dk in LDS, one barrier.
// Even/odd register buffers (compile-time indexed): pass p+2's loads are
// issued BEFORE converting p+1's data, so HBM always has outstanding loads.
__global__ __launch_bounds__(512, 2)
void mpo_main(const float* __restrict__ x, const _Float16* __restrict__ Wf,
              const float* __restrict__ dk, const float* __restrict__ bias,
              float* __restrict__ out) {
    extern __shared__ _Float16 Wl[];                       // 65536 halves + 256 floats
    float* dkL = reinterpret_cast<float*>(Wl + 65536);

    const int tid  = threadIdx.x;
    const int lane = tid & 63;
    const int wave = tid >> 6;        // 0..7
    const int lrow = lane & 15;
    const int g    = lane >> 4;

    const long blockbase = (long)blockIdx.x * 1024;
    const float* xb0 = x + (blockbase + wave * 16 + lrow) * 256 + g * 8;

    half8 a[8];
    floatx4 loE[8], hiE[8], loO[8], hiO[8];

#define SB()  __builtin_amdgcn_sched_barrier(0)
#define NTL(p) __builtin_nontemporal_load(reinterpret_cast<const floatx4*>(p))
#define XLDE(i, xn) do { const float* p_ = (xn) + (i) * 32; loE[i] = NTL(p_); hiE[i] = NTL(p_ + 4); } while (0)
#define XLDO(i, xn) do { const float* p_ = (xn) + (i) * 32; loO[i] = NTL(p_); hiO[i] = NTL(p_ + 4); } while (0)
#define XLDE_ALL(xn) do { XLDE(0,xn); XLDE(1,xn); XLDE(2,xn); XLDE(3,xn); \
                          XLDE(4,xn); XLDE(5,xn); XLDE(6,xn); XLDE(7,xn); } while (0)
#define XLDO_ALL(xn) do { XLDO(0,xn); XLDO(1,xn); XLDO(2,xn); XLDO(3,xn); \
                          XLDO(4,xn); XLDO(5,xn); XLDO(6,xn); XLDO(7,xn); } while (0)
#define XCVTE(i) do { half8 f_;                                                \
                     f_[0] = (_Float16)loE[i][0]; f_[1] = (_Float16)loE[i][1]; \
                     f_[2] = (_Float16)loE[i][2]; f_[3] = (_Float16)loE[i][3]; \
                     f_[4] = (_Float16)hiE[i][0]; f_[5] = (_Float16)hiE[i][1]; \
                     f_[6] = (_Float16)hiE[i][2]; f_[7] = (_Float16)hiE[i][3]; \
                     a[i] = f_; } while (0)
#define XCVTO(i) do { half8 f_;                                                \
                     f_[0] = (_Float16)loO[i][0]; f_[1] = (_Float16)loO[i][1]; \
                     f_[2] = (_Float16)loO[i][2]; f_[3] = (_Float16)loO[i][3]; \
                     f_[4] = (_Float16)hiO[i][0]; f_[5] = (_Float16)hiO[i][1]; \
                     f_[6] = (_Float16)hiO[i][2]; f_[7] = (_Float16)hiO[i][3]; \
                     a[i] = f_; } while (0)
#define XCVTE_ALL() do { XCVTE(0); XCVTE(1); XCVTE(2); XCVTE(3); \
                         XCVTE(4); XCVTE(5); XCVTE(6); XCVTE(7); } while (0)
#define XCVTO_ALL() do { XCVTO(0); XCVTO(1); XCVTO(2); XCVTO(3); \
                         XCVTO(4); XCVTO(5); XCVTO(6); XCVTO(7); } while (0)

#define NLOOP(rp) do {                                                           \
    _Pragma("unroll 1")                                                          \
    for (int n = 0; n < 16; ++n) {                                               \
        const float kv = dkL[n * 16 + lrow];                                     \
        const half8* Wn = Wv + n * 512 + lane;                                   \
        floatx4 c0 = {0, 0, 0, 0};                                               \
        _Pragma("unroll")                                                        \
        for (int kk = 0; kk < 8; ++kk)                                           \
            c0 = __builtin_amdgcn_mfma_f32_16x16x32_f16(a[kk], Wn[kk * 64], c0, 0, 0, 0); \
        _Pragma("unroll")                                                        \
        for (int r = 0; r < 4; ++r) rp[r] += c0[r] * c0[r] * kv;                 \
    } } while (0)

#define REDUCE_STORE(rp, p) do {                                                 \
    _Pragma("unroll")                                                            \
    for (int r = 0; r < 4; ++r) {                                                \
        float v = rp[r];                                                         \
        v += __shfl_xor(v, 1); v += __shfl_xor(v, 2);                            \
        v += __shfl_xor(v, 4); v += __shfl_xor(v, 8);                            \
        rp[r] = v;                                                               \
    }                                                                            \
    if (lrow == 0) {                                                             \
        floatx4 o;                                                               \
        _Pragma("unroll")                                                        \
        for (int r = 0; r < 4; ++r) o[r] = rp[r] * WSCALE_INV + bs;              \
        *reinterpret_cast<floatx4*>(out + blockbase + (p) * 128 + wave * 16 + g * 4) = o; \
    } } while (0)

    // ---- prologue: issue E(0); stage W+dk; sync; issue O(1); convert E(0) ----
    XLDE_ALL(xb0);
    SB();
    {
        const floatx4* src = reinterpret_cast<const floatx4*>(Wf);
        floatx4* dst = reinterpret_cast<floatx4*>(Wl);
#pragma unroll
        for (int i = 0; i < 16; ++i)
            dst[tid + i * 512] = src[tid + i * 512];
    }
    if (tid < 256) dkL[tid] = dk[tid];
    const float bs = bias[0];
    __syncthreads();
    XLDO_ALL(xb0 + 128 * 256);
    SB();
    XCVTE_ALL();
    SB();

    const half8* Wv = reinterpret_cast<const half8*>(Wl);

#pragma unroll 1
    for (int pp = 0; pp < 8; pp += 2) {
        // ---- even pass pp (a[] holds its fragments) ----
        {
            float rp[4] = {0, 0, 0, 0};
            NLOOP(rp);
            if (pp + 2 < 8) { XLDE_ALL(xb0 + (pp + 2) * (128 * 256)); }
            SB();
            REDUCE_STORE(rp, pp);
            XCVTO_ALL();            // a <- pass pp+1 (E(pp+2) stays in flight)
            SB();
        }
        // ---- odd pass pp+1 ----
        {
            float rp[4] = {0, 0, 0, 0};
            NLOOP(rp);
            if (pp + 3 < 8) { XLDO_ALL(xb0 + (pp + 3) * (128 * 256)); }
            SB();
            REDUCE_STORE(rp, pp + 1);
            if (pp + 2 < 8) { XCVTE_ALL(); }   // a <- pass pp+2
            SB();
        }
    }
}

extern "C" void kernel_launch(void* const* d_in, const int* in_sizes, int n_in,
                              void* d_out, int out_size, void* d_ws, size_t ws_size,
                              hipStream_t stream) {
    const float* x    = (const float*)d_in[0];
    const float* w    = (const float*)d_in[1];
    const float* dk   = (const float*)d_in[2];
    const float* bias = (const float*)d_in[3];
    float* out = (float*)d_out;
    float* ws  = (float*)d_ws;

    _Float16* Wf16 = (_Float16*)(ws + WF16_OFF);

    // Allow 129 KB dynamic LDS for mpo_main (host-side attr; validated R5-R8).
    static bool attr_set = false;
    if (!attr_set) {
        hipFuncSetAttribute((const void*)mpo_main,
                            hipFuncAttributeMaxDynamicSharedMemorySize, 132096);
        attr_set = true;
    }

    // W contraction: prep1 (2 register-tiled blocks), then prep2
    mpo_prep1<<<2, 256, 0, stream>>>(w, ws);
    mpo_prep2<<<256, 256, 0, stream>>>(ws, Wf16);

    // Main fused GEMM + square + dot: 256 blocks x 512 threads, 129 KB LDS
    mpo_main<<<256, 512, 132096, stream>>>(x, Wf16, dk, bias, out);
}